// Round 4
// baseline (10256.577 us; speedup 1.0000x reference)
//
#include <hip/hip_runtime.h>

// Stacked 2-layer tanh RNN, SEQ=512, B=64, IN=H=1024.
// Round 4: round-3 structure (batch-split across 8 XCDs, h-state in the XCD's
// own L2 via sc0, per-XCD 16+16 block cohorts pipelined one step apart,
// weights in VGPRs). Fix vs round 3: FULL unroll of every loop indexing the
// bw[] weight-fragment array (partial unroll left runtime indices -> the
// array was allocated in scratch, causing 17 GB/dispatch of spill traffic;
// rule #20). All bw indices are now compile-time constants.

typedef unsigned short ushort_t;
typedef unsigned int uint32;
typedef __attribute__((ext_vector_type(4))) unsigned int u32x4;
typedef __attribute__((ext_vector_type(4))) float f32x4;
typedef __attribute__((ext_vector_type(8))) __bf16 bfrag;

__device__ __forceinline__ f32x4 mfma_bf16(u32x4 a, u32x4 b, f32x4 c) {
  return __builtin_amdgcn_mfma_f32_16x16x32_bf16(
      __builtin_bit_cast(bfrag, a), __builtin_bit_cast(bfrag, b), c, 0, 0, 0);
}

__device__ __forceinline__ uint32 bf16rne(float f) {
  uint32 u = __builtin_bit_cast(uint32, f);
  return (u + 0x7fffu + ((u >> 16) & 1u)) >> 16;
}

__device__ __forceinline__ uint32 cvt_pk(float lo, float hi) {
  uint32 r;
  asm("v_cvt_pk_bf16_f32 %0, %1, %2" : "=v"(r) : "v"(lo), "v"(hi));
  return r;
}
__device__ __forceinline__ u32x4 pack8(f32x4 a, f32x4 b) {
  u32x4 r;
  r.x = cvt_pk(a.x, a.y);
  r.y = cvt_pk(a.z, a.w);
  r.z = cvt_pk(b.x, b.y);
  r.w = cvt_pk(b.z, b.w);
  return r;
}

// 16B L2-coherent load (bypass L1) with compile-time byte offset.
template <int BOFF>
__device__ __forceinline__ void ld16(u32x4& d, const ushort_t* base) {
  asm volatile("global_load_dwordx4 %0, %1, off offset:%c2 sc0"
               : "=v"(d) : "v"(base), "i"(BOFF) : "memory");
}

#define LOADB(BUF, AP, KOFF)                 \
  ld16<(KOFF) * 2 + 0>(BUF[0], AP);          \
  ld16<(KOFF) * 2 + 64>(BUF[1], AP);         \
  ld16<(KOFF) * 2 + 128>(BUF[2], AP);        \
  ld16<(KOFF) * 2 + 192>(BUF[3], AP);        \
  ld16<(KOFF) * 2 + 256>(BUF[4], AP);        \
  ld16<(KOFF) * 2 + 320>(BUF[5], AP);        \
  ld16<(KOFF) * 2 + 384>(BUF[6], AP);        \
  ld16<(KOFF) * 2 + 448>(BUF[7], AP);

// Bounded LLC poll (all lanes same address -> 1 request).
__device__ __forceinline__ void spin_ctr(const int* p, int tgt, int* ab) {
  int it = 0;
  for (;;) {
    int v;
    asm volatile("global_load_dword %0, %1, off sc0 sc1\n\ts_waitcnt vmcnt(0)"
                 : "=v"(v) : "v"(p) : "memory");
    if (v >= tgt) return;
    if ((++it & 1023) == 0) {
      int a;
      asm volatile("global_load_dword %0, %1, off sc0 sc1\n\ts_waitcnt vmcnt(0)"
                   : "=v"(a) : "v"(ab) : "memory");
      if (a) return;
      if (it > (1 << 21)) {
        int one = 1;
        asm volatile("global_store_dword %0, %1, off sc0 sc1\n\ts_waitcnt vmcnt(0)"
                     :: "v"(ab), "v"(one) : "memory");
        return;
      }
    }
  }
}

__global__ void rnn_init(int* c) {
  // zero slot/ctr0/ctr1 (8 XCDs x 3 x 32 ints) + abort flag, at LLC scope
  for (int k = threadIdx.x; k < 772; k += 256) {
    int z = 0;
    asm volatile("global_store_dword %0, %1, off sc0 sc1"
                 :: "v"(c + k), "v"(z) : "memory");
  }
  asm volatile("s_waitcnt vmcnt(0)" ::: "memory");
}

__global__ __launch_bounds__(512) void rnn_main(
    const float* __restrict__ Xt, const float* __restrict__ W0,
    const float* __restrict__ b0, const float* __restrict__ W1,
    const float* __restrict__ b1, float* __restrict__ Y,
    ushort_t* hbuf, int* cnt) {
  __shared__ float part[2][4][16][17];  // [buf][ntile][row16][feat16+pad]
  __shared__ int s_slot;

  const int tid = threadIdx.x;
  const int wave = tid >> 6;
  const int lane = tid & 63;
  const int ln15 = lane & 15;
  const int lq = lane >> 4;
  const int n = wave & 3;
  const bool fin = wave < 4;  // finisher waves (h-half K, tanh, stores)

  uint32 xcc;
  asm("s_getreg_b32 %0, hwreg(HW_REG_XCC_ID)" : "=s"(xcc));
  const int xcd = xcc & 7;

  int* slotp  = cnt + xcd * 96;
  int* ctr0   = cnt + xcd * 96 + 32;
  int* ctr1   = cnt + xcd * 96 + 64;
  int* abortp = cnt + 768;

  if (tid == 0) {
    int one = 1, old;
    asm volatile("global_atomic_add %0, %1, %2, off sc0 sc1\n\ts_waitcnt vmcnt(0)"
                 : "=v"(old) : "v"(slotp), "v"(one) : "memory");
    s_slot = old & 31;
  }
  __syncthreads();
  const int slot = s_slot;
  const bool isL1 = slot >= 16;
  const int F0 = (slot & 15) * 64;
  const int fcol = F0 + n * 16 + ln15;
  const int row8 = ln15 & 7;  // batch row (MFMA rows 8-15 duplicate 0-7, discarded)

  // K-half owned by this wave:
  //  L0: fin -> h0(t-1) half (k 1024..2047), partial -> x half (k 0..1023)
  //  L1: fin -> h0(t) half (k 0..1023),     partial -> h1(t-1) half (k 1024..2047)
  const int kh = isL1 ? (fin ? 0 : 1) : (fin ? 1 : 0);
  const float* Wsrc = isL1 ? W1 : W0;

  // Load + pack this wave's weight slice into 32 B-frags (128 VGPRs).
  // FULL unroll: every bw index must be a compile-time constant (rule #20).
  u32x4 bw[32];
  {
    const float* wp = Wsrc + (size_t)fcol * 2048 + kh * 1024 + lq * 8;
#pragma unroll
    for (int j = 0; j < 32; ++j) {
      f32x4 w0 = *(const f32x4*)(wp + j * 32);
      f32x4 w1 = *(const f32x4*)(wp + j * 32 + 4);
      bw[j] = pack8(w0, w1);
    }
  }
  const float bia = fin ? (isL1 ? b1 : b0)[fcol] : 0.f;

  ushort_t* h0b = hbuf + (size_t)xcd * 32768;  // [2][8][1024] bf16
  ushort_t* h1b = h0b + 16384;                 // [2][8][1024] bf16

  // K=1024 GEMM against L2-coherent h-state, double-buffered sc0 loads.
  auto gemm_h = [&](const ushort_t* hsrc) -> f32x4 {
    f32x4 a = {0.f, 0.f, 0.f, 0.f};
    const ushort_t* ap = hsrc + row8 * 1024 + lq * 8;
    u32x4 fa[8], fb[8];
    LOADB(fa, ap, 0);
    LOADB(fb, ap, 256);
    asm volatile("s_waitcnt vmcnt(8)" ::: "memory");
    __builtin_amdgcn_sched_barrier(0);
#pragma unroll
    for (int j = 0; j < 8; ++j) a = mfma_bf16(fa[j], bw[j], a);
    LOADB(fa, ap, 512);
    asm volatile("s_waitcnt vmcnt(8)" ::: "memory");
    __builtin_amdgcn_sched_barrier(0);
#pragma unroll
    for (int j = 0; j < 8; ++j) a = mfma_bf16(fb[j], bw[8 + j], a);
    LOADB(fb, ap, 768);
    asm volatile("s_waitcnt vmcnt(8)" ::: "memory");
    __builtin_amdgcn_sched_barrier(0);
#pragma unroll
    for (int j = 0; j < 8; ++j) a = mfma_bf16(fa[j], bw[16 + j], a);
    asm volatile("s_waitcnt vmcnt(0)" ::: "memory");
    __builtin_amdgcn_sched_barrier(0);
#pragma unroll
    for (int j = 0; j < 8; ++j) a = mfma_bf16(fb[j], bw[24 + j], a);
    return a;
  };

  // K=1024 GEMM against f32 X with on-the-fly bf16 pack (off critical path).
  // FULL unroll (bw indices compile-time).
  auto gemm_x = [&](int t) -> f32x4 {
    f32x4 a = {0.f, 0.f, 0.f, 0.f};
    const float* xp = Xt + ((size_t)t * 64 + xcd * 8 + row8) * 1024 + lq * 8;
#pragma unroll
    for (int j = 0; j < 32; ++j) {
      f32x4 x0 = *(const f32x4*)(xp + j * 32);
      f32x4 x1 = *(const f32x4*)(xp + j * 32 + 4);
      a = mfma_bf16(pack8(x0, x1), bw[j], a);
    }
    return a;
  };

  for (int t = 0; t < 512; ++t) {
    const int buf = t & 1;
    const int pb = (t - 1) & 1;
    f32x4 acc = {0.f, 0.f, 0.f, 0.f};

    if (!isL1) {
      if (fin) {
        if (t >= 1) spin_ctr(ctr0, 16 * t, abortp);        // h0(t-1) ready
        if (t >= 2) spin_ctr(ctr1, 16 * (t - 1), abortp);  // h0 slot reusable
        if (t >= 1) acc = gemm_h(h0b + pb * 8192);
      } else {
        acc = gemm_x(t);
      }
    } else {
      if (fin) {
        if (t >= 1) spin_ctr(ctr1, 16 * t, abortp);        // own cohort done t-1
        spin_ctr(ctr0, 16 * (t + 1), abortp);              // h0(t) ready
        acc = gemm_h(h0b + buf * 8192);
      } else {
        if (t >= 1) {
          spin_ctr(ctr1, 16 * t, abortp);                  // h1(t-1) ready
          acc = gemm_h(h1b + pb * 8192);
        }
      }
    }

    if (!fin) {
#pragma unroll
      for (int r = 0; r < 4; ++r) part[buf][n][lq * 4 + r][ln15] = acc[r];
    }
    __syncthreads();  // partial tiles visible

    if (fin) {
      float o[4];
#pragma unroll
      for (int r = 0; r < 4; ++r) {
        float s = acc[r] + part[buf][n][lq * 4 + r][ln15] + bia;
        float ax = fabsf(s);
        float e = __expf(2.f * ax);                  // inf-safe
        float rr = 1.f - 2.f * __builtin_amdgcn_rcpf(e + 1.f);
        o[r] = copysignf(rr, s);
      }
      if (lq < 2) {  // valid batch rows 0..7
        ushort_t* hd = (isL1 ? h1b : h0b) + buf * 8192 + (lq * 4) * 1024 + fcol;
#pragma unroll
        for (int r = 0; r < 4; ++r) {
          uint32 hv = bf16rne(o[r]);
          asm volatile("global_store_short %0, %1, off sc0"
                       :: "v"(hd + r * 1024), "v"(hv) : "memory");
        }
        if (isL1) {
          float* yd = Y + ((size_t)t * 64 + xcd * 8 + lq * 4) * 1024 + fcol;
#pragma unroll
          for (int r = 0; r < 4; ++r) yd[r * 1024] = o[r];
        }
      }
      asm volatile("s_waitcnt vmcnt(0)" ::: "memory");  // h in L2, Y accepted
    }
    __syncthreads();  // all fin stores drained

    if (tid == 0) {
      int one = 1;
      int* cp = isL1 ? ctr1 : ctr0;
      asm volatile("global_atomic_add %0, %1, off sc1" :: "v"(cp), "v"(one) : "memory");
    }
  }
}

extern "C" void kernel_launch(void* const* d_in, const int* in_sizes, int n_in,
                              void* d_out, int out_size, void* d_ws, size_t ws_size,
                              hipStream_t stream) {
  const float* Xt = (const float*)d_in[0];
  const float* W0 = (const float*)d_in[1];
  const float* b0 = (const float*)d_in[2];
  const float* W1 = (const float*)d_in[3];
  const float* b1 = (const float*)d_in[4];
  float* Y = (float*)d_out;

  int* cnt = (int*)d_ws;                                   // 3088 B used
  ushort_t* hbuf = (ushort_t*)((char*)d_ws + 4096);        // 512 KB h-state

  rnn_init<<<1, 256, 0, stream>>>(cnt);
  rnn_main<<<256, 512, 0, stream>>>(Xt, W0, b0, W1, b1, Y, hbuf, cnt);
}

// Round 5
// 6625.183 us; speedup vs baseline: 1.5481x; 1.5481x over previous
//
#include <hip/hip_runtime.h>

// Stacked 2-layer tanh RNN, SEQ=512, B=64, IN=H=1024.
// Round 5: same data structure as round 4 (batch-split across 8 XCDs, h-state
// in the XCD's own L2 via sc0, weights in VGPRs, per-XCD 16 L0-blocks + 16
// L1-blocks pipelined). Sync rework to kill the LLC poll storm:
//   - single polling wave per block (wave 0) + s_sleep backoff; other waves
//     released via __syncthreads.
//   - L0's X-GEMM overlaps the poll (runs pre-release), X(t+1) prefetched.
//   - h0 triple-buffered: L0's slot-reuse gate is ctr1 >= 16(t-2), off-path.

typedef unsigned short ushort_t;
typedef unsigned int uint32;
typedef __attribute__((ext_vector_type(4))) unsigned int u32x4;
typedef __attribute__((ext_vector_type(4))) float f32x4;
typedef __attribute__((ext_vector_type(8))) __bf16 bfrag;

__device__ __forceinline__ f32x4 mfma_bf16(u32x4 a, u32x4 b, f32x4 c) {
  return __builtin_amdgcn_mfma_f32_16x16x32_bf16(
      __builtin_bit_cast(bfrag, a), __builtin_bit_cast(bfrag, b), c, 0, 0, 0);
}

__device__ __forceinline__ uint32 bf16rne(float f) {
  uint32 u = __builtin_bit_cast(uint32, f);
  return (u + 0x7fffu + ((u >> 16) & 1u)) >> 16;
}

__device__ __forceinline__ uint32 cvt_pk(float lo, float hi) {
  uint32 r;
  asm("v_cvt_pk_bf16_f32 %0, %1, %2" : "=v"(r) : "v"(lo), "v"(hi));
  return r;
}
__device__ __forceinline__ u32x4 pack8(f32x4 a, f32x4 b) {
  u32x4 r;
  r.x = cvt_pk(a.x, a.y);
  r.y = cvt_pk(a.z, a.w);
  r.z = cvt_pk(b.x, b.y);
  r.w = cvt_pk(b.z, b.w);
  return r;
}

// 16B L2-coherent load (bypass L1) with compile-time byte offset.
template <int BOFF>
__device__ __forceinline__ void ld16(u32x4& d, const ushort_t* base) {
  asm volatile("global_load_dwordx4 %0, %1, off offset:%c2 sc0"
               : "=v"(d) : "v"(base), "i"(BOFF) : "memory");
}

#define LOADB(BUF, AP, KOFF)                 \
  ld16<(KOFF) * 2 + 0>(BUF[0], AP);          \
  ld16<(KOFF) * 2 + 64>(BUF[1], AP);         \
  ld16<(KOFF) * 2 + 128>(BUF[2], AP);        \
  ld16<(KOFF) * 2 + 192>(BUF[3], AP);        \
  ld16<(KOFF) * 2 + 256>(BUF[4], AP);        \
  ld16<(KOFF) * 2 + 320>(BUF[5], AP);        \
  ld16<(KOFF) * 2 + 384>(BUF[6], AP);        \
  ld16<(KOFF) * 2 + 448>(BUF[7], AP);

// LLC poll with s_sleep backoff; all lanes same address -> 1 request/poll.
// Returns 1 on abort.
__device__ __forceinline__ int poll_ge(const int* p, int tgt, int* ab) {
  for (int it = 0;; ++it) {
    int v;
    asm volatile("global_load_dword %0, %1, off sc0 sc1\n\ts_waitcnt vmcnt(0)"
                 : "=v"(v) : "v"(p) : "memory");
    if (v >= tgt) return 0;
    asm volatile("s_sleep 4" ::: "memory");
    if ((it & 255) == 255) {
      int a;
      asm volatile("global_load_dword %0, %1, off sc0 sc1\n\ts_waitcnt vmcnt(0)"
                   : "=v"(a) : "v"(ab) : "memory");
      if (a) return 1;
      if (it > (1 << 18)) {
        int one = 1;
        asm volatile("global_store_dword %0, %1, off sc0 sc1\n\ts_waitcnt vmcnt(0)"
                     :: "v"(ab), "v"(one) : "memory");
        return 1;
      }
    }
  }
}

__global__ void rnn_init(int* c) {
  // zero slot/ctr0/ctr1 (8 XCDs x 3 x 32 ints) + abort flag, at LLC scope
  for (int k = threadIdx.x; k < 772; k += 256) {
    int z = 0;
    asm volatile("global_store_dword %0, %1, off sc0 sc1"
                 :: "v"(c + k), "v"(z) : "memory");
  }
  asm volatile("s_waitcnt vmcnt(0)" ::: "memory");
}

__global__ __launch_bounds__(512) void rnn_main(
    const float* __restrict__ Xt, const float* __restrict__ W0,
    const float* __restrict__ b0, const float* __restrict__ W1,
    const float* __restrict__ b1, float* __restrict__ Y,
    ushort_t* hbuf, int* cnt) {
  __shared__ float part[2][4][16][17];  // [buf][ntile][row16][feat16+pad]
  __shared__ int s_slot;

  const int tid = threadIdx.x;
  const int wave = tid >> 6;
  const int lane = tid & 63;
  const int ln15 = lane & 15;
  const int lq = lane >> 4;
  const int n = wave & 3;
  const bool fin = wave < 4;  // finisher waves (h-half K, tanh, stores)

  uint32 xcc;
  asm("s_getreg_b32 %0, hwreg(HW_REG_XCC_ID)" : "=s"(xcc));
  const int xcd = xcc & 7;

  int* slotp  = cnt + xcd * 96;
  int* ctr0   = cnt + xcd * 96 + 32;
  int* ctr1   = cnt + xcd * 96 + 64;
  int* abortp = cnt + 768;

  if (tid == 0) {
    int one = 1, old;
    asm volatile("global_atomic_add %0, %1, %2, off sc0 sc1\n\ts_waitcnt vmcnt(0)"
                 : "=v"(old) : "v"(slotp), "v"(one) : "memory");
    s_slot = old & 31;
  }
  __syncthreads();
  const int slot = s_slot;
  const bool isL1 = slot >= 16;
  const int F0 = (slot & 15) * 64;
  const int fcol = F0 + n * 16 + ln15;
  const int row8 = ln15 & 7;  // batch row (MFMA rows 8-15 duplicate 0-7, discarded)

  // K-half owned by this wave:
  //  L0: fin -> h0(t-1) half (k 1024..2047), partial -> x half (k 0..1023)
  //  L1: fin -> h0(t) half (k 0..1023),     partial -> h1(t-1) half (k 1024..2047)
  const int kh = isL1 ? (fin ? 0 : 1) : (fin ? 1 : 0);
  const float* Wsrc = isL1 ? W1 : W0;

  // Load + pack this wave's weight slice into 32 B-frags (128 VGPRs).
  // FULL unroll everywhere bw is indexed (rule #20).
  u32x4 bw[32];
  {
    const float* wp = Wsrc + (size_t)fcol * 2048 + kh * 1024 + lq * 8;
#pragma unroll
    for (int j = 0; j < 32; ++j) {
      f32x4 w0 = *(const f32x4*)(wp + j * 32);
      f32x4 w1 = *(const f32x4*)(wp + j * 32 + 4);
      bw[j] = pack8(w0, w1);
    }
  }
  const float bia = fin ? (isL1 ? b1 : b0)[fcol] : 0.f;

  ushort_t* h0b = hbuf + (size_t)xcd * 40960;  // [3][8][1024] bf16 (triple buf)
  ushort_t* h1b = h0b + 24576;                 // [2][8][1024] bf16

  // K=1024 GEMM against L2-coherent h-state, double-buffered sc0 loads.
  auto gemm_h = [&](const ushort_t* hsrc) -> f32x4 {
    f32x4 a = {0.f, 0.f, 0.f, 0.f};
    const ushort_t* ap = hsrc + row8 * 1024 + lq * 8;
    u32x4 fa[8], fb[8];
    LOADB(fa, ap, 0);
    LOADB(fb, ap, 256);
    asm volatile("s_waitcnt vmcnt(8)" ::: "memory");
    __builtin_amdgcn_sched_barrier(0);
#pragma unroll
    for (int j = 0; j < 8; ++j) a = mfma_bf16(fa[j], bw[j], a);
    LOADB(fa, ap, 512);
    asm volatile("s_waitcnt vmcnt(8)" ::: "memory");
    __builtin_amdgcn_sched_barrier(0);
#pragma unroll
    for (int j = 0; j < 8; ++j) a = mfma_bf16(fb[j], bw[8 + j], a);
    LOADB(fb, ap, 768);
    asm volatile("s_waitcnt vmcnt(8)" ::: "memory");
    __builtin_amdgcn_sched_barrier(0);
#pragma unroll
    for (int j = 0; j < 8; ++j) a = mfma_bf16(fa[j], bw[16 + j], a);
    asm volatile("s_waitcnt vmcnt(0)" ::: "memory");
    __builtin_amdgcn_sched_barrier(0);
#pragma unroll
    for (int j = 0; j < 8; ++j) a = mfma_bf16(fb[j], bw[24 + j], a);
    return a;
  };

  // K=1024 GEMM against f32 X with on-the-fly bf16 pack (pre-release overlap).
  auto gemm_x = [&](int t) -> f32x4 {
    f32x4 a = {0.f, 0.f, 0.f, 0.f};
    const float* xp = Xt + ((size_t)t * 64 + xcd * 8 + row8) * 1024 + lq * 8;
#pragma unroll
    for (int j = 0; j < 32; ++j) {
      f32x4 x0 = *(const f32x4*)(xp + j * 32);
      f32x4 x1 = *(const f32x4*)(xp + j * 32 + 4);
      a = mfma_bf16(pack8(x0, x1), bw[j], a);
    }
    return a;
  };

  for (int t = 0; t < 512; ++t) {
    const int buf = t & 1;
    f32x4 acc = {0.f, 0.f, 0.f, 0.f};
    uint32 pf0 = 0, pf1 = 0;

    // ---- pre-release: wave0 polls; L0 partials compute X-GEMM + prefetch ----
    if (!isL1) {
      if (fin) {
        if (wave == 0) {
          if (t >= 1) poll_ge(ctr0, 16 * t, abortp);        // h0(t-1) ready
          if (t >= 2) poll_ge(ctr1, 16 * (t - 2), abortp);  // h0 slot reusable
        }
      } else {
        {  // prefetch next step's X slice (one dword per 64B line)
          int tn = t < 511 ? t + 1 : 511;
          const char* pfp = (const char*)(Xt + ((size_t)tn * 64 + xcd * 8) * 1024)
                            + n * 8192 + lane * 128;
          asm volatile("global_load_dword %0, %1, off" : "=v"(pf0) : "v"(pfp));
          asm volatile("global_load_dword %0, %1, off offset:64" : "=v"(pf1) : "v"(pfp));
        }
        acc = gemm_x(t);
#pragma unroll
        for (int r = 0; r < 4; ++r) part[buf][n][lq * 4 + r][ln15] = acc[r];
      }
    } else {
      if (wave == 0) {
        if (t >= 1) poll_ge(ctr1, 16 * t, abortp);          // own cohort done t-1
        poll_ge(ctr0, 16 * (t + 1), abortp);                // h0(t) ready
      }
    }
    __syncthreads();  // B0: release (counters satisfied)

    // ---- post-release GEMMs against L2-resident h-state ----
    if (!isL1) {
      if (fin && t >= 1) acc = gemm_h(h0b + ((t - 1) % 3) * 8192);
    } else {
      if (fin) {
        acc = gemm_h(h0b + (t % 3) * 8192);
      } else {
        if (t >= 1) acc = gemm_h(h1b + ((t - 1) & 1) * 8192);
#pragma unroll
        for (int r = 0; r < 4; ++r) part[buf][n][lq * 4 + r][ln15] = acc[r];
      }
    }
    if (!fin) asm volatile("" :: "v"(pf0), "v"(pf1));  // keep prefetch alive
    __syncthreads();  // B1: partials visible

    if (fin) {
      float o[4];
#pragma unroll
      for (int r = 0; r < 4; ++r) {
        float s = acc[r] + part[buf][n][lq * 4 + r][ln15] + bia;
        float ax = fabsf(s);
        float e = __expf(2.f * ax);                  // inf-safe
        float rr = 1.f - 2.f * __builtin_amdgcn_rcpf(e + 1.f);
        o[r] = copysignf(rr, s);
      }
      if (lq < 2) {  // valid batch rows 0..7
        ushort_t* hd = (isL1 ? h1b + (t & 1) * 8192 : h0b + (t % 3) * 8192)
                       + (lq * 4) * 1024 + fcol;
#pragma unroll
        for (int r = 0; r < 4; ++r) {
          uint32 hv = bf16rne(o[r]);
          asm volatile("global_store_short %0, %1, off sc0"
                       :: "v"(hd + r * 1024), "v"(hv) : "memory");
        }
        if (isL1) {
          float* yd = Y + ((size_t)t * 64 + xcd * 8 + lq * 4) * 1024 + fcol;
#pragma unroll
          for (int r = 0; r < 4; ++r) yd[r * 1024] = o[r];
        }
      }
      asm volatile("s_waitcnt vmcnt(0)" ::: "memory");  // h in L2, Y accepted
    }
    __syncthreads();  // B2: all fin stores drained

    if (tid == 0) {
      int one = 1;
      int* cp = isL1 ? ctr1 : ctr0;
      asm volatile("global_atomic_add %0, %1, off sc1" :: "v"(cp), "v"(one) : "memory");
    }
  }
}

extern "C" void kernel_launch(void* const* d_in, const int* in_sizes, int n_in,
                              void* d_out, int out_size, void* d_ws, size_t ws_size,
                              hipStream_t stream) {
  const float* Xt = (const float*)d_in[0];
  const float* W0 = (const float*)d_in[1];
  const float* b0 = (const float*)d_in[2];
  const float* W1 = (const float*)d_in[3];
  const float* b1 = (const float*)d_in[4];
  float* Y = (float*)d_out;

  int* cnt = (int*)d_ws;                                   // 3088 B used
  ushort_t* hbuf = (ushort_t*)((char*)d_ws + 4096);        // 640 KB h-state

  rnn_init<<<1, 256, 0, stream>>>(cnt);
  rnn_main<<<256, 512, 0, stream>>>(Xt, W0, b0, W1, b1, Y, hbuf, cnt);
}

// Round 7
// 6310.710 us; speedup vs baseline: 1.6253x; 1.0498x over previous
//
#include <hip/hip_runtime.h>

// Stacked 2-layer tanh RNN, SEQ=512, B=64, IN=H=1024.
// Round 7: round-6 structure with sync restored to the PROVEN scope:
//   - per-block flags published with ONE plain system-scope store (sc0 sc1)
//     -> replaces rounds 2-5's 16-deep LLC atomic-RMW train (the ~10us/step).
//     (store->poll at sc0 sc1 is round-1-proven across XCDs; round 6's plain
//      sc0 flags were the unproven link and failed.)
//   - one poller wave per block gathers all 16+16 flags in ONE per-lane load
//     + __all ballot; s_sleep 2 backoff.
// Data path unchanged (proven rounds 2-5): batch-split across 8 XCDs, h-state
// in the XCD's L2 via sc0, weights in VGPRs (full unroll, rule #20), per-XCD
// 16 L0-blocks + 16 L1-blocks pipelined one step apart, h0 triple-buffered.

typedef unsigned short ushort_t;
typedef unsigned int uint32;
typedef __attribute__((ext_vector_type(4))) unsigned int u32x4;
typedef __attribute__((ext_vector_type(4))) float f32x4;
typedef __attribute__((ext_vector_type(8))) __bf16 bfrag;

__device__ __forceinline__ f32x4 mfma_bf16(u32x4 a, u32x4 b, f32x4 c) {
  return __builtin_amdgcn_mfma_f32_16x16x32_bf16(
      __builtin_bit_cast(bfrag, a), __builtin_bit_cast(bfrag, b), c, 0, 0, 0);
}

__device__ __forceinline__ uint32 bf16rne(float f) {
  uint32 u = __builtin_bit_cast(uint32, f);
  return (u + 0x7fffu + ((u >> 16) & 1u)) >> 16;
}

__device__ __forceinline__ uint32 cvt_pk(float lo, float hi) {
  uint32 r;
  asm("v_cvt_pk_bf16_f32 %0, %1, %2" : "=v"(r) : "v"(lo), "v"(hi));
  return r;
}
__device__ __forceinline__ u32x4 pack8(f32x4 a, f32x4 b) {
  u32x4 r;
  r.x = cvt_pk(a.x, a.y);
  r.y = cvt_pk(a.z, a.w);
  r.z = cvt_pk(b.x, b.y);
  r.w = cvt_pk(b.z, b.w);
  return r;
}

// 16B L2-coherent load (bypass L1) with compile-time byte offset.
template <int BOFF>
__device__ __forceinline__ void ld16(u32x4& d, const ushort_t* base) {
  asm volatile("global_load_dwordx4 %0, %1, off offset:%c2 sc0"
               : "=v"(d) : "v"(base), "i"(BOFF) : "memory");
}

#define LOADB(BUF, AP, KOFF)                 \
  ld16<(KOFF) * 2 + 0>(BUF[0], AP);          \
  ld16<(KOFF) * 2 + 64>(BUF[1], AP);         \
  ld16<(KOFF) * 2 + 128>(BUF[2], AP);        \
  ld16<(KOFF) * 2 + 192>(BUF[3], AP);        \
  ld16<(KOFF) * 2 + 256>(BUF[4], AP);        \
  ld16<(KOFF) * 2 + 320>(BUF[5], AP);        \
  ld16<(KOFF) * 2 + 384>(BUF[6], AP);        \
  ld16<(KOFF) * 2 + 448>(BUF[7], AP);

__global__ void rnn_init(int* c) {
  // zero per-XCD flag regions (8 x 1024 ints) + abort flag, at system scope
  for (int k = threadIdx.x; k < 8193; k += 256) {
    int z = 0;
    asm volatile("global_store_dword %0, %1, off sc0 sc1"
                 :: "v"(c + k), "v"(z) : "memory");
  }
  asm volatile("s_waitcnt vmcnt(0)" ::: "memory");
}

__global__ __launch_bounds__(512) void rnn_main(
    const float* __restrict__ Xt, const float* __restrict__ W0,
    const float* __restrict__ b0, const float* __restrict__ W1,
    const float* __restrict__ b1, float* __restrict__ Y,
    ushort_t* hbuf, int* cnt) {
  __shared__ float part[2][4][16][17];  // [buf][ntile][row16][feat16+pad]
  __shared__ int s_slot;

  const int tid = threadIdx.x;
  const int wave = tid >> 6;
  const int lane = tid & 63;
  const int ln15 = lane & 15;
  const int lq = lane >> 4;
  const int n = wave & 3;
  const bool fin = wave < 4;  // finisher waves (h-half K, tanh, stores)

  uint32 xcc;
  asm("s_getreg_b32 %0, hwreg(HW_REG_XCC_ID)" : "=s"(xcc));
  const int xcd = xcc & 7;

  int* fbase  = cnt + xcd * 1024;  // per-XCD: [0]=slot, [16+i*16]=flag0[i],
                                   //          [528+i*16]=flag1[i]  (64B lines)
  int* abortp = cnt + 8192;

  if (tid == 0) {
    int one = 1, old;
    asm volatile("global_atomic_add %0, %1, %2, off sc0 sc1\n\ts_waitcnt vmcnt(0)"
                 : "=v"(old) : "v"(fbase), "v"(one) : "memory");
    s_slot = old & 31;
  }
  __syncthreads();
  const int slot = s_slot;
  const bool isL1 = slot >= 16;
  const int F0 = (slot & 15) * 64;
  const int fcol = F0 + n * 16 + ln15;
  const int row8 = ln15 & 7;  // batch row (MFMA rows 8-15 duplicate 0-7, discarded)

  // Poller gather setup (wave 0): lanes 0-15 -> flag0[i], 16-31 -> flag1[i],
  // 32-63 -> flag0[0] with always-true target.
  const int* myf = (lane < 16) ? (fbase + 16 + ln15 * 16)
                  : (lane < 32) ? (fbase + 528 + ln15 * 16)
                                : (fbase + 16);
  int* myflag = fbase + (isL1 ? 528 : 16) + (slot & 15) * 16;

  // K-half owned by this wave:
  //  L0: fin -> h0(t-1) half (k 1024..2047), partial -> x half (k 0..1023)
  //  L1: fin -> h0(t) half (k 0..1023),     partial -> h1(t-1) half (k 1024..2047)
  const int kh = isL1 ? (fin ? 0 : 1) : (fin ? 1 : 0);
  const float* Wsrc = isL1 ? W1 : W0;

  // Load + pack this wave's weight slice into 32 B-frags (128 VGPRs).
  // FULL unroll everywhere bw is indexed (rule #20).
  u32x4 bw[32];
  {
    const float* wp = Wsrc + (size_t)fcol * 2048 + kh * 1024 + lq * 8;
#pragma unroll
    for (int j = 0; j < 32; ++j) {
      f32x4 w0 = *(const f32x4*)(wp + j * 32);
      f32x4 w1 = *(const f32x4*)(wp + j * 32 + 4);
      bw[j] = pack8(w0, w1);
    }
  }
  const float bia = fin ? (isL1 ? b1 : b0)[fcol] : 0.f;

  ushort_t* h0b = hbuf + (size_t)xcd * 40960;  // [3][8][1024] bf16 (triple buf)
  ushort_t* h1b = h0b + 24576;                 // [2][8][1024] bf16

  // K=1024 GEMM against L2-coherent h-state, double-buffered sc0 loads.
  auto gemm_h = [&](const ushort_t* hsrc) -> f32x4 {
    f32x4 a = {0.f, 0.f, 0.f, 0.f};
    const ushort_t* ap = hsrc + row8 * 1024 + lq * 8;
    u32x4 fa[8], fb[8];
    LOADB(fa, ap, 0);
    LOADB(fb, ap, 256);
    asm volatile("s_waitcnt vmcnt(8)" ::: "memory");
    __builtin_amdgcn_sched_barrier(0);
#pragma unroll
    for (int j = 0; j < 8; ++j) a = mfma_bf16(fa[j], bw[j], a);
    LOADB(fa, ap, 512);
    asm volatile("s_waitcnt vmcnt(8)" ::: "memory");
    __builtin_amdgcn_sched_barrier(0);
#pragma unroll
    for (int j = 0; j < 8; ++j) a = mfma_bf16(fb[j], bw[8 + j], a);
    LOADB(fb, ap, 768);
    asm volatile("s_waitcnt vmcnt(8)" ::: "memory");
    __builtin_amdgcn_sched_barrier(0);
#pragma unroll
    for (int j = 0; j < 8; ++j) a = mfma_bf16(fa[j], bw[16 + j], a);
    asm volatile("s_waitcnt vmcnt(0)" ::: "memory");
    __builtin_amdgcn_sched_barrier(0);
#pragma unroll
    for (int j = 0; j < 8; ++j) a = mfma_bf16(fb[j], bw[24 + j], a);
    return a;
  };

  // K=1024 GEMM against f32 X with on-the-fly bf16 pack (pre-release overlap).
  auto gemm_x = [&](int t) -> f32x4 {
    f32x4 a = {0.f, 0.f, 0.f, 0.f};
    const float* xp = Xt + ((size_t)t * 64 + xcd * 8 + row8) * 1024 + lq * 8;
#pragma unroll
    for (int j = 0; j < 32; ++j) {
      f32x4 x0 = *(const f32x4*)(xp + j * 32);
      f32x4 x1 = *(const f32x4*)(xp + j * 32 + 4);
      a = mfma_bf16(pack8(x0, x1), bw[j], a);
    }
    return a;
  };

  for (int t = 0; t < 512; ++t) {
    const int buf = t & 1;
    f32x4 acc = {0.f, 0.f, 0.f, 0.f};
    uint32 pf0 = 0, pf1 = 0;

    // ---- pre-release: wave0 polls flags; L0 partials do X-GEMM + prefetch ----
    if (wave == 0) {
      // L0 step t needs: flag0[*] >= t (cohort done t-1, h0(t-1) readable)
      //                  flag1[*] >= t-2 (h0 slot t%3 consumed)
      // L1 step t needs: flag0[*] >= t+1 (h0(t) ready)
      //                  flag1[*] >= t (own cohort done t-1, h1(t-1) readable)
      const int tA = isL1 ? t + 1 : t;
      const int tB = isL1 ? t : t - 2;
      const int tgt = (lane < 16) ? tA : (lane < 32) ? tB : -2000000000;
      if (tA > 0) {
        for (int it = 0;; ++it) {
          int v;
          asm volatile("global_load_dword %0, %1, off sc0 sc1\n\ts_waitcnt vmcnt(0)"
                       : "=v"(v) : "v"(myf) : "memory");
          if (__all(v >= tgt)) break;
          asm volatile("s_sleep 2" ::: "memory");
          if ((it & 255) == 255) {
            int a;
            asm volatile("global_load_dword %0, %1, off sc0 sc1\n\ts_waitcnt vmcnt(0)"
                         : "=v"(a) : "v"(abortp) : "memory");
            if (a) break;
            if (it > (1 << 18)) {
              int one = 1;
              asm volatile("global_store_dword %0, %1, off sc0 sc1\n\ts_waitcnt vmcnt(0)"
                           :: "v"(abortp), "v"(one) : "memory");
              break;
            }
          }
        }
      }
    } else if (!isL1 && !fin) {
      {  // prefetch next step's X slice (one dword per 64B line)
        int tn = t < 511 ? t + 1 : 511;
        const char* pfp = (const char*)(Xt + ((size_t)tn * 64 + xcd * 8) * 1024)
                          + n * 8192 + lane * 128;
        asm volatile("global_load_dword %0, %1, off" : "=v"(pf0) : "v"(pfp));
        asm volatile("global_load_dword %0, %1, off offset:64" : "=v"(pf1) : "v"(pfp));
      }
      acc = gemm_x(t);
#pragma unroll
      for (int r = 0; r < 4; ++r) part[buf][n][lq * 4 + r][ln15] = acc[r];
    }
    __syncthreads();  // B0: release (flag conditions satisfied)

    // ---- post-release GEMMs against L2-resident h-state ----
    if (!isL1) {
      if (fin && t >= 1) acc = gemm_h(h0b + ((t - 1) % 3) * 8192);
    } else {
      if (fin) {
        acc = gemm_h(h0b + (t % 3) * 8192);
      } else {
        if (t >= 1) acc = gemm_h(h1b + ((t - 1) & 1) * 8192);
#pragma unroll
        for (int r = 0; r < 4; ++r) part[buf][n][lq * 4 + r][ln15] = acc[r];
      }
    }
    if (!fin) asm volatile("" :: "v"(pf0), "v"(pf1));  // keep prefetch alive
    __syncthreads();  // B1: partials visible

    if (fin) {
      float o[4];
#pragma unroll
      for (int r = 0; r < 4; ++r) {
        float s = acc[r] + part[buf][n][lq * 4 + r][ln15] + bia;
        float ax = fabsf(s);
        float e = __expf(2.f * ax);                  // inf-safe
        float rr = 1.f - 2.f * __builtin_amdgcn_rcpf(e + 1.f);
        o[r] = copysignf(rr, s);
      }
      if (lq < 2) {  // valid batch rows 0..7
        ushort_t* hd = (isL1 ? h1b + (t & 1) * 8192 : h0b + (t % 3) * 8192)
                       + (lq * 4) * 1024 + fcol;
#pragma unroll
        for (int r = 0; r < 4; ++r) {
          uint32 hv = bf16rne(o[r]);
          asm volatile("global_store_short %0, %1, off sc0"
                       :: "v"(hd + r * 1024), "v"(hv) : "memory");
        }
        if (isL1) {
          float* yd = Y + ((size_t)t * 64 + xcd * 8 + lq * 4) * 1024 + fcol;
#pragma unroll
          for (int r = 0; r < 4; ++r) yd[r * 1024] = o[r];
        }
      }
      asm volatile("s_waitcnt vmcnt(0)" ::: "memory");  // h landed in L2
    }
    __syncthreads();  // B2: all fin stores drained

    if (tid == 0) {  // publish: ONE plain system-scope store to own flag line
      int val = t + 1;
      asm volatile("global_store_dword %0, %1, off sc0 sc1"
                   :: "v"(myflag), "v"(val) : "memory");
    }
  }
}

extern "C" void kernel_launch(void* const* d_in, const int* in_sizes, int n_in,
                              void* d_out, int out_size, void* d_ws, size_t ws_size,
                              hipStream_t stream) {
  const float* Xt = (const float*)d_in[0];
  const float* W0 = (const float*)d_in[1];
  const float* b0 = (const float*)d_in[2];
  const float* W1 = (const float*)d_in[3];
  const float* b1 = (const float*)d_in[4];
  float* Y = (float*)d_out;

  int* cnt = (int*)d_ws;                                   // 32,772 B used
  ushort_t* hbuf = (ushort_t*)((char*)d_ws + 36864);       // 640 KB h-state

  rnn_init<<<1, 256, 0, stream>>>(cnt);
  rnn_main<<<256, 512, 0, stream>>>(Xt, W0, b0, W1, b1, Y, hbuf, cnt);
}

// Round 8
// 6076.319 us; speedup vs baseline: 1.6880x; 1.0386x over previous
//
#include <hip/hip_runtime.h>

// Stacked 2-layer tanh RNN, SEQ=512, B=64, IN=H=1024.
// Round 8: within-XCD fast sync arrows through the XCD L2.
//   publish: dual — plain sc0 store into a per-cohort 16-dword (64B) fast
//            line (L2) + the proven R7 sc0sc1 LLC flag (fallback path).
//   poll:    wave0 reads the fast line via s_dcache_inv + s_load_dwordx4
//            (scalar cache is L2-backed -> always L2-fresh; defeats the L1
//            staleness that sank round 6's vector-sc0 polls).
//   safety:  fast path only for flag targets >= 2 (publishes of step>=1 are
//            transitively ordered after in-kernel zeroing of the fast lines
//            via the step-0/1 LLC gates); sticky per-block LLC fallback after
//            512 fast rounds. Worst case = round 7 + ~75us.
// Data path unchanged (proven R2-R7): batch-split across 8 XCDs, h-state in
// XCD L2 via sc0, weights in VGPRs (full unroll, rule #20), 16 L0 + 16 L1
// blocks per XCD pipelined one step apart, h0 triple-buffered.

typedef unsigned short ushort_t;
typedef unsigned int uint32;
typedef __attribute__((ext_vector_type(4))) int i32x4;
typedef __attribute__((ext_vector_type(4))) unsigned int u32x4;
typedef __attribute__((ext_vector_type(4))) float f32x4;
typedef __attribute__((ext_vector_type(8))) __bf16 bfrag;

__device__ __forceinline__ f32x4 mfma_bf16(u32x4 a, u32x4 b, f32x4 c) {
  return __builtin_amdgcn_mfma_f32_16x16x32_bf16(
      __builtin_bit_cast(bfrag, a), __builtin_bit_cast(bfrag, b), c, 0, 0, 0);
}

__device__ __forceinline__ uint32 bf16rne(float f) {
  uint32 u = __builtin_bit_cast(uint32, f);
  return (u + 0x7fffu + ((u >> 16) & 1u)) >> 16;
}

__device__ __forceinline__ uint32 cvt_pk(float lo, float hi) {
  uint32 r;
  asm("v_cvt_pk_bf16_f32 %0, %1, %2" : "=v"(r) : "v"(lo), "v"(hi));
  return r;
}
__device__ __forceinline__ u32x4 pack8(f32x4 a, f32x4 b) {
  u32x4 r;
  r.x = cvt_pk(a.x, a.y);
  r.y = cvt_pk(a.z, a.w);
  r.z = cvt_pk(b.x, b.y);
  r.w = cvt_pk(b.z, b.w);
  return r;
}

// 16B L2-coherent load (bypass L1) with compile-time byte offset.
template <int BOFF>
__device__ __forceinline__ void ld16(u32x4& d, const ushort_t* base) {
  asm volatile("global_load_dwordx4 %0, %1, off offset:%c2 sc0"
               : "=v"(d) : "v"(base), "i"(BOFF) : "memory");
}

#define LOADB(BUF, AP, KOFF)                 \
  ld16<(KOFF) * 2 + 0>(BUF[0], AP);          \
  ld16<(KOFF) * 2 + 64>(BUF[1], AP);         \
  ld16<(KOFF) * 2 + 128>(BUF[2], AP);        \
  ld16<(KOFF) * 2 + 192>(BUF[3], AP);        \
  ld16<(KOFF) * 2 + 256>(BUF[4], AP);        \
  ld16<(KOFF) * 2 + 320>(BUF[5], AP);        \
  ld16<(KOFF) * 2 + 384>(BUF[6], AP);        \
  ld16<(KOFF) * 2 + 448>(BUF[7], AP);

// Scalar read of one 64B fast-flag line (16 dwords) via sK$ backed by L2.
__device__ __forceinline__ int line_min16(const int* p, int doInv) {
  i32x4 q0, q1, q2, q3;
  if (doInv) asm volatile("s_dcache_inv" ::: "memory");
  asm volatile(
      "s_load_dwordx4 %0, %4, 0x0\n\t"
      "s_load_dwordx4 %1, %4, 0x10\n\t"
      "s_load_dwordx4 %2, %4, 0x20\n\t"
      "s_load_dwordx4 %3, %4, 0x30\n\t"
      "s_waitcnt lgkmcnt(0)"
      : "=s"(q0), "=s"(q1), "=s"(q2), "=s"(q3)
      : "s"(p) : "memory");
  int m = min(min(q0.x, q0.y), min(q0.z, q0.w));
  m = min(m, min(min(q1.x, q1.y), min(q1.z, q1.w)));
  m = min(m, min(min(q2.x, q2.y), min(q2.z, q2.w)));
  m = min(m, min(min(q3.x, q3.y), min(q3.z, q3.w)));
  return m;
}

__global__ void rnn_init(int* c) {
  // zero per-XCD flag regions (8 x 1024 ints) + abort flag, at system scope
  for (int k = threadIdx.x; k < 8193; k += 256) {
    int z = 0;
    asm volatile("global_store_dword %0, %1, off sc0 sc1"
                 :: "v"(c + k), "v"(z) : "memory");
  }
  asm volatile("s_waitcnt vmcnt(0)" ::: "memory");
}

__global__ __launch_bounds__(512) void rnn_main(
    const float* __restrict__ Xt, const float* __restrict__ W0,
    const float* __restrict__ b0, const float* __restrict__ W1,
    const float* __restrict__ b1, float* __restrict__ Y,
    ushort_t* hbuf, int* cnt) {
  __shared__ float part[2][4][16][17];  // [buf][ntile][row16][feat16+pad]
  __shared__ int s_slot;

  const int tid = threadIdx.x;
  const int wave = tid >> 6;
  const int lane = tid & 63;
  const int ln15 = lane & 15;
  const int lq = lane >> 4;
  const int n = wave & 3;
  const bool fin = wave < 4;  // finisher waves (h-half K, tanh, stores)

  uint32 xcc;
  asm("s_getreg_b32 %0, hwreg(HW_REG_XCC_ID)" : "=s"(xcc));
  const int xcd = xcc & 7;

  int* fbase  = cnt + xcd * 1024;  // per-XCD: [0]=slot, [16+i*16]=flag0[i],
                                   // [528+i*16]=flag1[i] (LLC, 64B lines),
                                   // [896..911]=fast fl0, [912..927]=fast fl1
  int* abortp = cnt + 8192;

  if (tid == 0) {
    int one = 1, old;
    asm volatile("global_atomic_add %0, %1, %2, off sc0 sc1\n\ts_waitcnt vmcnt(0)"
                 : "=v"(old) : "v"(fbase), "v"(one) : "memory");
    s_slot = old & 31;
  }
  __syncthreads();
  const int slot = s_slot;
  const bool isL1 = slot >= 16;
  const int F0 = (slot & 15) * 64;
  const int fcol = F0 + n * 16 + ln15;
  const int row8 = ln15 & 7;  // batch row (MFMA rows 8-15 duplicate 0-7, discarded)

  const int* fl0p = fbase + 896;  // fast line, L0 cohort (16 dwords)
  const int* fl1p = fbase + 912;  // fast line, L1 cohort
  int* fastflag = fbase + (isL1 ? 912 : 896) + (slot & 15);

  // LLC poller gather setup (wave 0): lanes 0-15 -> flag0[i], 16-31 -> flag1[i].
  const int* myf = (lane < 16) ? (fbase + 16 + ln15 * 16)
                  : (lane < 32) ? (fbase + 528 + ln15 * 16)
                                : (fbase + 16);
  int* slowflag = fbase + (isL1 ? 528 : 16) + (slot & 15) * 16;

  // In-kernel zero of this cohort's fast line by slot-0 block (ordered before
  // any fast publish via the step-0/1 LLC gates; drained by wave0's step-0
  // fin vmcnt(0) which precedes its step-0 LLC publish).
  if ((slot & 15) == 0 && tid < 16) {
    int z = 0;
    asm volatile("global_store_dword %0, %1, off sc0"
                 :: "v"((int*)(fbase + (isL1 ? 912 : 896) + tid)), "v"(z) : "memory");
  }

  // K-half owned by this wave:
  //  L0: fin -> h0(t-1) half (k 1024..2047), partial -> x half (k 0..1023)
  //  L1: fin -> h0(t) half (k 0..1023),     partial -> h1(t-1) half (k 1024..2047)
  const int kh = isL1 ? (fin ? 0 : 1) : (fin ? 1 : 0);
  const float* Wsrc = isL1 ? W1 : W0;

  // Load + pack this wave's weight slice into 32 B-frags (128 VGPRs).
  // FULL unroll everywhere bw is indexed (rule #20).
  u32x4 bw[32];
  {
    const float* wp = Wsrc + (size_t)fcol * 2048 + kh * 1024 + lq * 8;
#pragma unroll
    for (int j = 0; j < 32; ++j) {
      f32x4 w0 = *(const f32x4*)(wp + j * 32);
      f32x4 w1 = *(const f32x4*)(wp + j * 32 + 4);
      bw[j] = pack8(w0, w1);
    }
  }
  const float bia = fin ? (isL1 ? b1 : b0)[fcol] : 0.f;

  ushort_t* h0b = hbuf + (size_t)xcd * 40960;  // [3][8][1024] bf16 (triple buf)
  ushort_t* h1b = h0b + 24576;                 // [2][8][1024] bf16

  // K=1024 GEMM against L2-coherent h-state, double-buffered sc0 loads.
  auto gemm_h = [&](const ushort_t* hsrc) -> f32x4 {
    f32x4 a = {0.f, 0.f, 0.f, 0.f};
    const ushort_t* ap = hsrc + row8 * 1024 + lq * 8;
    u32x4 fa[8], fb[8];
    LOADB(fa, ap, 0);
    LOADB(fb, ap, 256);
    asm volatile("s_waitcnt vmcnt(8)" ::: "memory");
    __builtin_amdgcn_sched_barrier(0);
#pragma unroll
    for (int j = 0; j < 8; ++j) a = mfma_bf16(fa[j], bw[j], a);
    LOADB(fa, ap, 512);
    asm volatile("s_waitcnt vmcnt(8)" ::: "memory");
    __builtin_amdgcn_sched_barrier(0);
#pragma unroll
    for (int j = 0; j < 8; ++j) a = mfma_bf16(fb[j], bw[8 + j], a);
    LOADB(fb, ap, 768);
    asm volatile("s_waitcnt vmcnt(8)" ::: "memory");
    __builtin_amdgcn_sched_barrier(0);
#pragma unroll
    for (int j = 0; j < 8; ++j) a = mfma_bf16(fa[j], bw[16 + j], a);
    asm volatile("s_waitcnt vmcnt(0)" ::: "memory");
    __builtin_amdgcn_sched_barrier(0);
#pragma unroll
    for (int j = 0; j < 8; ++j) a = mfma_bf16(fb[j], bw[24 + j], a);
    return a;
  };

  // K=1024 GEMM against f32 X with on-the-fly bf16 pack (pre-release overlap).
  auto gemm_x = [&](int t) -> f32x4 {
    f32x4 a = {0.f, 0.f, 0.f, 0.f};
    const float* xp = Xt + ((size_t)t * 64 + xcd * 8 + row8) * 1024 + lq * 8;
#pragma unroll
    for (int j = 0; j < 32; ++j) {
      f32x4 x0 = *(const f32x4*)(xp + j * 32);
      f32x4 x1 = *(const f32x4*)(xp + j * 32 + 4);
      a = mfma_bf16(pack8(x0, x1), bw[j], a);
    }
    return a;
  };

  int mode = 0;  // 0 = fast (L2 scalar) arrows; 1 = sticky LLC fallback

  for (int t = 0; t < 512; ++t) {
    const int buf = t & 1;
    f32x4 acc = {0.f, 0.f, 0.f, 0.f};
    uint32 pf0 = 0, pf1 = 0;

    // ---- pre-release: wave0 gates; L0 partials do X-GEMM + prefetch ----
    if (wave == 0) {
      // L0 t: flag0[*] >= t (cohort done t-1); flag1[*] >= t-2 (slot reuse)
      // L1 t: flag0[*] >= t+1 (h0(t) ready); flag1[*] >= t (cohort done t-1)
      const int tA = isL1 ? t + 1 : t;
      const int tB = isL1 ? t : t - 2;
      const bool needA = tA >= 1, needB = tB >= 1;
      const bool eligA = needA && tA >= 2 && !mode;
      const bool eligB = needB && tB >= 2 && !mode;
      bool fastDone = false;
      if (eligA || eligB) {
        for (int it = 0; it < 512; ++it) {
          int mA = line_min16(fl0p, 1);
          int mB = line_min16(fl1p, 0);
          if ((!eligA || mA >= tA) && (!eligB || mB >= tB)) { fastDone = true; break; }
          asm volatile("s_sleep 1" ::: "memory");
        }
        if (!fastDone) mode = 1;  // sticky fallback to LLC flags
      }
      const bool llcA = needA && (!eligA || !fastDone);
      const bool llcB = needB && (!eligB || !fastDone);
      if (llcA || llcB) {
        const int tgt = (lane < 16) ? (llcA ? tA : (int)0x80000000)
                       : (lane < 32) ? (llcB ? tB : (int)0x80000000)
                                     : (int)0x80000000;
        for (int it = 0;; ++it) {
          int v;
          asm volatile("global_load_dword %0, %1, off sc0 sc1\n\ts_waitcnt vmcnt(0)"
                       : "=v"(v) : "v"(myf) : "memory");
          if (__all(v >= tgt)) break;
          asm volatile("s_sleep 2" ::: "memory");
          if ((it & 255) == 255) {
            int a;
            asm volatile("global_load_dword %0, %1, off sc0 sc1\n\ts_waitcnt vmcnt(0)"
                         : "=v"(a) : "v"(abortp) : "memory");
            if (a) break;
            if (it > (1 << 18)) {
              int one = 1;
              asm volatile("global_store_dword %0, %1, off sc0 sc1\n\ts_waitcnt vmcnt(0)"
                           :: "v"(abortp), "v"(one) : "memory");
              break;
            }
          }
        }
      }
    } else if (!isL1 && !fin) {
      {  // prefetch next step's X slice (one dword per 64B line)
        int tn = t < 511 ? t + 1 : 511;
        const char* pfp = (const char*)(Xt + ((size_t)tn * 64 + xcd * 8) * 1024)
                          + n * 8192 + lane * 128;
        asm volatile("global_load_dword %0, %1, off" : "=v"(pf0) : "v"(pfp));
        asm volatile("global_load_dword %0, %1, off offset:64" : "=v"(pf1) : "v"(pfp));
      }
      acc = gemm_x(t);
#pragma unroll
      for (int r = 0; r < 4; ++r) part[buf][n][lq * 4 + r][ln15] = acc[r];
    }
    __syncthreads();  // B0: release (flag conditions satisfied)

    // ---- post-release GEMMs against L2-resident h-state ----
    if (!isL1) {
      if (fin && t >= 1) acc = gemm_h(h0b + ((t - 1) % 3) * 8192);
    } else {
      if (fin) {
        acc = gemm_h(h0b + (t % 3) * 8192);
      } else {
        if (t >= 1) acc = gemm_h(h1b + ((t - 1) & 1) * 8192);
#pragma unroll
        for (int r = 0; r < 4; ++r) part[buf][n][lq * 4 + r][ln15] = acc[r];
      }
    }
    if (!fin) asm volatile("" :: "v"(pf0), "v"(pf1));  // keep prefetch alive
    __syncthreads();  // B1: partials visible

    if (fin) {
      float o[4];
#pragma unroll
      for (int r = 0; r < 4; ++r) {
        float s = acc[r] + part[buf][n][lq * 4 + r][ln15] + bia;
        float ax = fabsf(s);
        float e = __expf(2.f * ax);                  // inf-safe
        float rr = 1.f - 2.f * __builtin_amdgcn_rcpf(e + 1.f);
        o[r] = copysignf(rr, s);
      }
      if (lq < 2) {  // valid batch rows 0..7
        ushort_t* hd = (isL1 ? h1b + (t & 1) * 8192 : h0b + (t % 3) * 8192)
                       + (lq * 4) * 1024 + fcol;
#pragma unroll
        for (int r = 0; r < 4; ++r) {
          uint32 hv = bf16rne(o[r]);
          asm volatile("global_store_short %0, %1, off sc0"
                       :: "v"(hd + r * 1024), "v"(hv) : "memory");
        }
        if (isL1) {
          float* yd = Y + ((size_t)t * 64 + xcd * 8 + lq * 4) * 1024 + fcol;
#pragma unroll
          for (int r = 0; r < 4; ++r) yd[r * 1024] = o[r];
        }
      }
      asm volatile("s_waitcnt vmcnt(0)" ::: "memory");  // h (and zeros) in L2
    }
    __syncthreads();  // B2: all fin stores drained

    if (tid == 0) {  // dual publish: fast L2 line (t>=1) + proven LLC flag
      int val = t + 1;
      if (t >= 1)
        asm volatile("global_store_dword %0, %1, off sc0"
                     :: "v"(fastflag), "v"(val) : "memory");
      asm volatile("global_store_dword %0, %1, off sc0 sc1"
                   :: "v"(slowflag), "v"(val) : "memory");
    }
  }
}

extern "C" void kernel_launch(void* const* d_in, const int* in_sizes, int n_in,
                              void* d_out, int out_size, void* d_ws, size_t ws_size,
                              hipStream_t stream) {
  const float* Xt = (const float*)d_in[0];
  const float* W0 = (const float*)d_in[1];
  const float* b0 = (const float*)d_in[2];
  const float* W1 = (const float*)d_in[3];
  const float* b1 = (const float*)d_in[4];
  float* Y = (float*)d_out;

  int* cnt = (int*)d_ws;                                   // 32,772 B used
  ushort_t* hbuf = (ushort_t*)((char*)d_ws + 36864);       // 640 KB h-state

  rnn_init<<<1, 256, 0, stream>>>(cnt);
  rnn_main<<<256, 512, 0, stream>>>(Xt, W0, b0, W1, b1, Y, hbuf, cnt);
}